// Round 1
// baseline (1288.124 us; speedup 1.0000x reference)
//
#include <hip/hip_runtime.h>
#include <math.h>

#define T_ 64
#define B_ 32
#define S_ 50
#define M_ 2048      // T*B
#define V_ 50000     // VOCAB
#define K_ 512       // RNN_SIZE
#define EPS 1e-10f

typedef unsigned short ushort_t;
typedef __attribute__((ext_vector_type(8))) short short8;
typedef __attribute__((ext_vector_type(4))) float float4v;

__device__ inline ushort_t f2bf(float f) {
    union { float f; unsigned u; } x; x.f = f;
    unsigned u = x.u;
    u += 0x7fffu + ((u >> 16) & 1u);   // round-to-nearest-even
    return (ushort_t)(u >> 16);
}

// ---------------------------------------------------------------------------
// K1: logits = hidden @ W^T + b   (M x V, K=512), bf16 MFMA, fp32 output
// BM=BN=128, BK=64, 256 threads = 4 waves in 2x2, each wave 64x64 (4x4 MFMA)
// ---------------------------------------------------------------------------
__global__ __launch_bounds__(256) void gemm_logits(
    const float* __restrict__ A,     // hidden  M x K row-major
    const float* __restrict__ W,     // weights V x K row-major (B^T layout)
    const float* __restrict__ bias,  // V
    float* __restrict__ out)         // M x V logits
{
    __shared__ ushort_t As[128 * 64];
    __shared__ ushort_t Bs[128 * 64];

    const int tid  = threadIdx.x;
    const int lane = tid & 63;
    const int w    = tid >> 6;
    const int wm   = w >> 1;      // 0..1
    const int wn   = w & 1;       // 0..1
    const int m0   = blockIdx.x * 128;
    const int n0   = blockIdx.y * 128;

    float4v acc[4][4] = {};

    for (int k0 = 0; k0 < K_; k0 += 64) {
        // stage A-tile and B-tile: 128x64 fp32 -> bf16 in LDS
        #pragma unroll
        for (int it = 0; it < 8; ++it) {
            const int fidx = it * 256 + tid;     // float4 index, 2048 per tile
            const int row  = fidx >> 4;          // 16 float4 per 64-wide row
            const int kc   = (fidx & 15) << 2;

            const float4v va = *(const float4v*)&A[(size_t)(m0 + row) * K_ + k0 + kc];
            union { ushort_t u[4]; unsigned long long ll; } pa;
            pa.u[0] = f2bf(va.x); pa.u[1] = f2bf(va.y);
            pa.u[2] = f2bf(va.z); pa.u[3] = f2bf(va.w);
            *(unsigned long long*)&As[row * 64 + kc] = pa.ll;

            const int gn = n0 + row;
            float4v vb = (float4v){0.f, 0.f, 0.f, 0.f};
            if (gn < V_) vb = *(const float4v*)&W[(size_t)gn * K_ + k0 + kc];
            union { ushort_t u[4]; unsigned long long ll; } pb;
            pb.u[0] = f2bf(vb.x); pb.u[1] = f2bf(vb.y);
            pb.u[2] = f2bf(vb.z); pb.u[3] = f2bf(vb.w);
            *(unsigned long long*)&Bs[row * 64 + kc] = pb.ll;
        }
        __syncthreads();

        #pragma unroll
        for (int kk = 0; kk < 64; kk += 32) {
            short8 af[4], bf[4];
            #pragma unroll
            for (int t = 0; t < 4; ++t) {
                af[t] = *(const short8*)&As[(wm * 64 + t * 16 + (lane & 15)) * 64 + kk + (lane >> 4) * 8];
                bf[t] = *(const short8*)&Bs[(wn * 64 + t * 16 + (lane & 15)) * 64 + kk + (lane >> 4) * 8];
            }
            #pragma unroll
            for (int mt = 0; mt < 4; ++mt)
                #pragma unroll
                for (int nt = 0; nt < 4; ++nt)
                    acc[mt][nt] = __builtin_amdgcn_mfma_f32_16x16x32_bf16(
                        af[mt], bf[nt], acc[mt][nt], 0, 0, 0);
        }
        __syncthreads();
    }

    // epilogue: C[row=(lane>>4)*4+r][col=lane&15] + bias
    #pragma unroll
    for (int mt = 0; mt < 4; ++mt) {
        const int rbase = m0 + wm * 64 + mt * 16 + (lane >> 4) * 4;
        #pragma unroll
        for (int nt = 0; nt < 4; ++nt) {
            const int col = n0 + wn * 64 + nt * 16 + (lane & 15);
            if (col < V_) {
                const float bv = bias[col];
                #pragma unroll
                for (int r = 0; r < 4; ++r)
                    out[(size_t)(rbase + r) * V_ + col] = acc[mt][nt][r] + bv;
            }
        }
    }
}

// ---------------------------------------------------------------------------
// K2: per-row stats: Z = sum_{j!=4} exp(l_j), copy = sigmoid(l_4),
//     norm = (1-copy)(1 - e^{l0}/Z) + copy*sum_{idx!=0} attn + eps,
//     A_i = (1-copy)/(Z*norm); plus the <=52 special column values.
// ---------------------------------------------------------------------------
__global__ __launch_bounds__(256) void rowstats(
    const float* __restrict__ logits, const float* __restrict__ attn,
    const int* __restrict__ src, const int* __restrict__ alignment,
    float* __restrict__ Ai, float* __restrict__ c0v, float* __restrict__ c4v,
    float* __restrict__ tval)
{
    const int i   = blockIdx.x;
    const int b   = i & (B_ - 1);       // batch = i % 32 (rows are t-major)
    const int tid = threadIdx.x;
    const float* row = &logits[(size_t)i * V_];

    float local = 0.f;
    for (int x = tid; x < V_ / 4; x += 256) {
        const float4v v = *(const float4v*)&row[x * 4];
        local += __expf(v.x) + __expf(v.y) + __expf(v.z) + __expf(v.w);
    }
    __shared__ float red[4];
    float s = local;
    #pragma unroll
    for (int off = 32; off > 0; off >>= 1) s += __shfl_down(s, off);
    if ((tid & 63) == 0) red[tid >> 6] = s;

    __shared__ int   sj[S_];
    __shared__ float sat[S_];
    if (tid < S_) {
        sj[tid]  = alignment[src[b * S_ + tid]];
        sat[tid] = attn[i * S_ + tid];
    }
    __syncthreads();

    __shared__ float sh[3];   // Z, copy, norm
    if (tid == 0) {
        const float l4   = row[4];
        const float Z    = red[0] + red[1] + red[2] + red[3] - __expf(l4);
        const float copy = 1.f / (1.f + __expf(-l4));
        const float l0   = row[0];
        float anz = 0.f, a4 = 0.f;
        for (int t = 0; t < S_; ++t) {
            anz += (sj[t] != 0) ? sat[t] : 0.f;
            a4  += (sj[t] == 4) ? sat[t] : 0.f;
        }
        const float norm = (1.f - copy) * (1.f - __expf(l0) / Z) + copy * anz + EPS;
        Ai[i]  = (1.f - copy) / (Z * norm);
        c0v[i] = __logf(EPS / norm + EPS);
        c4v[i] = __logf(copy * a4 / norm + EPS);
        sh[0] = Z; sh[1] = copy; sh[2] = norm;
    }
    __syncthreads();

    if (tid < S_) {
        const float Z = sh[0], copy = sh[1], norm = sh[2];
        const int j = sj[tid];
        float val;
        if (j == 0) {
            val = __logf(EPS / norm + EPS);
        } else {
            float sum = 0.f;   // combine duplicate targets -> identical values
            for (int t = 0; t < S_; ++t) sum += (sj[t] == j) ? sat[t] : 0.f;
            const float pj = (j == 4) ? 0.f : __expf(row[j]) * (1.f - copy) / Z;
            val = __logf((pj + copy * sum) / norm + EPS);
        }
        tval[i * S_ + tid] = val;
    }
}

// ---------------------------------------------------------------------------
// K3: in-place generic transform: out = log(exp(l) * A_row + eps)
// ---------------------------------------------------------------------------
__global__ __launch_bounds__(256) void transform(
    float* __restrict__ out, const float* __restrict__ Ai)
{
    const int i = blockIdx.y;
    const int x = blockIdx.x * 256 + threadIdx.x;
    if (x >= V_ / 4) return;
    const float a = Ai[i];
    float4v v = *(float4v*)&out[(size_t)i * V_ + x * 4];
    v.x = __logf(fmaf(__expf(v.x), a, EPS));
    v.y = __logf(fmaf(__expf(v.y), a, EPS));
    v.z = __logf(fmaf(__expf(v.z), a, EPS));
    v.w = __logf(fmaf(__expf(v.w), a, EPS));
    *(float4v*)&out[(size_t)i * V_ + x * 4] = v;
}

// ---------------------------------------------------------------------------
// K4: scatter fixup — overwrite special columns with precomputed values.
// Duplicate j write identical values, so plain stores are race-safe.
// ---------------------------------------------------------------------------
__global__ __launch_bounds__(64) void fixup(
    float* __restrict__ out, const int* __restrict__ src,
    const int* __restrict__ alignment, const float* __restrict__ tval,
    const float* __restrict__ c0v, const float* __restrict__ c4v)
{
    const int i = blockIdx.x;
    const int b = i & (B_ - 1);
    const int t = threadIdx.x;
    if (t < S_) {
        const int j = alignment[src[b * S_ + t]];
        out[(size_t)i * V_ + j] = tval[i * S_ + t];
    } else if (t == S_) {
        out[(size_t)i * V_ + 0] = c0v[i];
    } else if (t == S_ + 1) {
        out[(size_t)i * V_ + 4] = c4v[i];
    }
}

extern "C" void kernel_launch(void* const* d_in, const int* in_sizes, int n_in,
                              void* d_out, int out_size, void* d_ws, size_t ws_size,
                              hipStream_t stream)
{
    const float* hidden    = (const float*)d_in[0];
    const float* attn      = (const float*)d_in[1];
    const float* W         = (const float*)d_in[2];
    const float* bias      = (const float*)d_in[3];
    const int*   src       = (const int*)d_in[4];
    const int*   alignment = (const int*)d_in[5];
    float* out = (float*)d_out;

    float* ws   = (float*)d_ws;
    float* Ai   = ws;            // 2048
    float* c0v  = ws + 2048;     // 2048
    float* c4v  = ws + 4096;     // 2048
    float* tval = ws + 6144;     // 2048*50  -> total ~434 KB of ws

    dim3 g1(M_ / 128, (V_ + 127) / 128);   // 16 x 391
    gemm_logits<<<g1, 256, 0, stream>>>(hidden, W, bias, out);
    rowstats<<<M_, 256, 0, stream>>>(out, attn, src, alignment, Ai, c0v, c4v, tval);
    transform<<<dim3((V_ / 4 + 255) / 256, M_), 256, 0, stream>>>(out, Ai);
    fixup<<<M_, 64, 0, stream>>>(out, src, alignment, tval, c0v, c4v);
}

// Round 2
// 850.304 us; speedup vs baseline: 1.5149x; 1.5149x over previous
//
#include <hip/hip_runtime.h>
#include <math.h>

#define T_ 64
#define B_ 32
#define S_ 50
#define M_ 2048      // T*B
#define V_ 50000     // VOCAB
#define VPAD_ 50048  // 391 * 128
#define K_ 512       // RNN_SIZE
#define EPS 1e-10f

typedef unsigned short ushort_t;
typedef __attribute__((ext_vector_type(8))) short short8;
typedef __attribute__((ext_vector_type(4))) float float4v;

__device__ inline ushort_t f2bf(float f) {
    union { float f; unsigned u; } x; x.f = f;
    unsigned u = x.u;
    u += 0x7fffu + ((u >> 16) & 1u);   // round-to-nearest-even
    return (ushort_t)(u >> 16);
}

// ---------------------------------------------------------------------------
// zero Zpart (2048 floats) — no hipMemsetAsync to stay graph-capture-safe
// ---------------------------------------------------------------------------
__global__ __launch_bounds__(256) void zeroZ(float* __restrict__ Z) {
    const int i = blockIdx.x * 256 + threadIdx.x;
    if (i < M_) Z[i] = 0.f;
}

// ---------------------------------------------------------------------------
// fp32 -> bf16 converters (run every call; ws is re-poisoned by harness)
// ---------------------------------------------------------------------------
__global__ __launch_bounds__(256) void convert_w(
    const float* __restrict__ W, ushort_t* __restrict__ Wbf)
{
    const int c   = blockIdx.x * 256 + threadIdx.x;  // chunk of 8 elems
    const int row = c >> 6;                          // 64 chunks per 512-row
    const int kc  = (c & 63) << 3;
    union { ushort_t u[8]; float4v f; } pk;
    if (row < V_) {
        const float4v a = *(const float4v*)&W[(size_t)row * K_ + kc];
        const float4v b = *(const float4v*)&W[(size_t)row * K_ + kc + 4];
        pk.u[0] = f2bf(a.x); pk.u[1] = f2bf(a.y); pk.u[2] = f2bf(a.z); pk.u[3] = f2bf(a.w);
        pk.u[4] = f2bf(b.x); pk.u[5] = f2bf(b.y); pk.u[6] = f2bf(b.z); pk.u[7] = f2bf(b.w);
    } else {
        pk.f = (float4v){0.f, 0.f, 0.f, 0.f};
    }
    *(float4v*)&Wbf[(size_t)c * 8] = pk.f;
}

__global__ __launch_bounds__(256) void convert_h(
    const float* __restrict__ H, ushort_t* __restrict__ Hbf)
{
    const int c  = blockIdx.x * 256 + threadIdx.x;
    const int kc = c << 3;
    const float4v a = *(const float4v*)&H[kc];
    const float4v b = *(const float4v*)&H[kc + 4];
    union { ushort_t u[8]; float4v f; } pk;
    pk.u[0] = f2bf(a.x); pk.u[1] = f2bf(a.y); pk.u[2] = f2bf(a.z); pk.u[3] = f2bf(a.w);
    pk.u[4] = f2bf(b.x); pk.u[5] = f2bf(b.y); pk.u[6] = f2bf(b.z); pk.u[7] = f2bf(b.w);
    *(float4v*)&Hbf[(size_t)c * 8] = pk.f;
}

// ---------------------------------------------------------------------------
// Fast GEMM: logits = Hbf @ Wbf^T + b, m97-style global_load_lds staging,
// XOR-swizzled LDS layout (conflict-free frag reads), fused Z=sum(exp) epilogue.
// 128x128 tile, BK=64, 256 threads = 4 waves (2x2), wave = 64x64 via 4x4 MFMA.
// LDS chunk slot c (16B = 8 bf16): row r = c>>3, k-chunk stored = (c&7)^(r&7).
// ---------------------------------------------------------------------------
__global__ __launch_bounds__(256) void gemm_fast(
    const ushort_t* __restrict__ Hbf,  // M x K bf16
    const ushort_t* __restrict__ Wbf,  // VPAD x K bf16 (zero-padded)
    const float* __restrict__ bias,    // V
    float* __restrict__ out,           // M x V fp32 logits
    float* __restrict__ Zpart)         // M, atomic exp-sum accumulator
{
    __shared__ ushort_t As[128 * 64];
    __shared__ ushort_t Bs[128 * 64];

    const int tid  = threadIdx.x;
    const int lane = tid & 63;
    const int w    = tid >> 6;
    const int wm   = w >> 1;
    const int wn   = w & 1;
    const int m0   = blockIdx.x * 128;
    const int n0   = blockIdx.y * 128;

    float4v acc[4][4] = {};

    for (int k0 = 0; k0 < K_; k0 += 64) {
        // stage A and B tiles: 1024 chunks of 16B each, 256 lanes x 4 iters.
        // LDS dest is contiguous in lane order (HW requirement); the XOR
        // swizzle is applied on the GLOBAL side (which chunk each lane loads).
        #pragma unroll
        for (int it = 0; it < 4; ++it) {
            const int c   = it * 256 + tid;
            const int r   = c >> 3;
            const int jgl = (c & 7) ^ (r & 7);          // swizzled k-chunk
            const size_t goffA = (size_t)(m0 + r) * K_ + k0 + jgl * 8;
            __builtin_amdgcn_global_load_lds(
                (const __attribute__((address_space(1))) unsigned int*)(const void*)(Hbf + goffA),
                (__attribute__((address_space(3))) unsigned int*)(void*)(As + (size_t)c * 8),
                16, 0, 0);
        }
        #pragma unroll
        for (int it = 0; it < 4; ++it) {
            const int c   = it * 256 + tid;
            const int r   = c >> 3;
            const int jgl = (c & 7) ^ (r & 7);
            const size_t goffB = (size_t)(n0 + r) * K_ + k0 + jgl * 8;
            __builtin_amdgcn_global_load_lds(
                (const __attribute__((address_space(1))) unsigned int*)(const void*)(Wbf + goffB),
                (__attribute__((address_space(3))) unsigned int*)(void*)(Bs + (size_t)c * 8),
                16, 0, 0);
        }
        __syncthreads();

        #pragma unroll
        for (int kk = 0; kk < 64; kk += 32) {
            const int jf = (kk >> 3) + (lane >> 4);     // k-chunk this lane needs
            short8 af[4], bf[4];
            #pragma unroll
            for (int t = 0; t < 4; ++t) {
                const int ra = wm * 64 + t * 16 + (lane & 15);
                af[t] = *(const short8*)&As[(size_t)(ra * 8 + (jf ^ (ra & 7))) * 8];
                const int rb = wn * 64 + t * 16 + (lane & 15);
                bf[t] = *(const short8*)&Bs[(size_t)(rb * 8 + (jf ^ (rb & 7))) * 8];
            }
            #pragma unroll
            for (int mt = 0; mt < 4; ++mt)
                #pragma unroll
                for (int nt = 0; nt < 4; ++nt)
                    acc[mt][nt] = __builtin_amdgcn_mfma_f32_16x16x32_bf16(
                        af[mt], bf[nt], acc[mt][nt], 0, 0, 0);
        }
        __syncthreads();
    }

    // epilogue: C[row=(lane>>4)*4+r][col=lane&15] + bias; write logits and
    // accumulate Z = sum_j exp(logit_j) per row (COPY col subtracted later).
    #pragma unroll
    for (int mt = 0; mt < 4; ++mt) {
        const int rbase = m0 + wm * 64 + mt * 16 + (lane >> 4) * 4;
        float esum[4] = {0.f, 0.f, 0.f, 0.f};
        #pragma unroll
        for (int nt = 0; nt < 4; ++nt) {
            const int col = n0 + wn * 64 + nt * 16 + (lane & 15);
            if (col < V_) {
                const float bv = bias[col];
                #pragma unroll
                for (int r = 0; r < 4; ++r) {
                    const float v = acc[mt][nt][r] + bv;
                    out[(size_t)(rbase + r) * V_ + col] = v;
                    esum[r] += __expf(v);
                }
            }
        }
        #pragma unroll
        for (int r = 0; r < 4; ++r) {
            float s = esum[r];
            s += __shfl_xor(s, 1);
            s += __shfl_xor(s, 2);
            s += __shfl_xor(s, 4);
            s += __shfl_xor(s, 8);
            if ((lane & 15) == 0) atomicAdd(&Zpart[rbase + r], s);
        }
    }
}

// ---------------------------------------------------------------------------
// Tiny per-row stats (Z comes from the GEMM epilogue; no 410MB re-read)
// ---------------------------------------------------------------------------
__global__ __launch_bounds__(64) void stats(
    const float* __restrict__ logits, const float* __restrict__ attn,
    const int* __restrict__ src, const int* __restrict__ alignment,
    const float* __restrict__ Zpart,
    float* __restrict__ Ai, float* __restrict__ c0v, float* __restrict__ c4v,
    float* __restrict__ tval)
{
    const int i   = blockIdx.x;
    const int b   = i & (B_ - 1);
    const int tid = threadIdx.x;

    __shared__ int   sj[S_];
    __shared__ float sat[S_];
    if (tid < S_) {
        sj[tid]  = alignment[src[b * S_ + tid]];
        sat[tid] = attn[i * S_ + tid];
    }
    __syncthreads();

    __shared__ float sh[3];   // Z, copy, norm
    if (tid == 0) {
        const float l4   = logits[(size_t)i * V_ + 4];
        const float Z    = Zpart[i] - __expf(l4);
        const float copy = 1.f / (1.f + __expf(-l4));
        const float l0   = logits[(size_t)i * V_];
        float anz = 0.f, a4 = 0.f;
        for (int t = 0; t < S_; ++t) {
            anz += (sj[t] != 0) ? sat[t] : 0.f;
            a4  += (sj[t] == 4) ? sat[t] : 0.f;
        }
        const float norm = (1.f - copy) * (1.f - __expf(l0) / Z) + copy * anz + EPS;
        Ai[i]  = (1.f - copy) / (Z * norm);
        c0v[i] = __logf(EPS / norm + EPS);
        c4v[i] = __logf(copy * a4 / norm + EPS);
        sh[0] = Z; sh[1] = copy; sh[2] = norm;
    }
    __syncthreads();

    if (tid < S_) {
        const float Z = sh[0], copy = sh[1], norm = sh[2];
        const int j = sj[tid];
        float val;
        if (j == 0) {
            val = __logf(EPS / norm + EPS);
        } else {
            float sum = 0.f;   // duplicate targets -> identical values
            for (int t = 0; t < S_; ++t) sum += (sj[t] == j) ? sat[t] : 0.f;
            const float pj = (j == 4) ? 0.f : __expf(logits[(size_t)i * V_ + j]) * (1.f - copy) / Z;
            val = __logf((pj + copy * sum) / norm + EPS);
        }
        tval[i * S_ + tid] = val;
    }
}

// ---------------------------------------------------------------------------
// generic transform: out = log(exp(l) * A_row + eps), in place
// ---------------------------------------------------------------------------
__global__ __launch_bounds__(256) void transform(
    float* __restrict__ out, const float* __restrict__ Ai)
{
    const int i = blockIdx.y;
    const int x = blockIdx.x * 256 + threadIdx.x;
    if (x >= V_ / 4) return;
    const float a = Ai[i];
    float4v v = *(float4v*)&out[(size_t)i * V_ + x * 4];
    v.x = __logf(fmaf(__expf(v.x), a, EPS));
    v.y = __logf(fmaf(__expf(v.y), a, EPS));
    v.z = __logf(fmaf(__expf(v.z), a, EPS));
    v.w = __logf(fmaf(__expf(v.w), a, EPS));
    *(float4v*)&out[(size_t)i * V_ + x * 4] = v;
}

// ---------------------------------------------------------------------------
// scatter fixup — duplicates write identical values, race-safe
// ---------------------------------------------------------------------------
__global__ __launch_bounds__(64) void fixup(
    float* __restrict__ out, const int* __restrict__ src,
    const int* __restrict__ alignment, const float* __restrict__ tval,
    const float* __restrict__ c0v, const float* __restrict__ c4v)
{
    const int i = blockIdx.x;
    const int b = i & (B_ - 1);
    const int t = threadIdx.x;
    if (t < S_) {
        const int j = alignment[src[b * S_ + t]];
        out[(size_t)i * V_ + j] = tval[i * S_ + t];
    } else if (t == S_) {
        out[(size_t)i * V_ + 0] = c0v[i];
    } else if (t == S_ + 1) {
        out[(size_t)i * V_ + 4] = c4v[i];
    }
}

// ======================= fallback (round-1) path ===========================
__global__ __launch_bounds__(256) void gemm_logits(
    const float* __restrict__ A, const float* __restrict__ W,
    const float* __restrict__ bias, float* __restrict__ out)
{
    __shared__ ushort_t As[128 * 64];
    __shared__ ushort_t Bs[128 * 64];
    const int tid  = threadIdx.x;
    const int lane = tid & 63;
    const int w    = tid >> 6;
    const int wm   = w >> 1;
    const int wn   = w & 1;
    const int m0   = blockIdx.x * 128;
    const int n0   = blockIdx.y * 128;
    float4v acc[4][4] = {};
    for (int k0 = 0; k0 < K_; k0 += 64) {
        #pragma unroll
        for (int it = 0; it < 8; ++it) {
            const int fidx = it * 256 + tid;
            const int row  = fidx >> 4;
            const int kc   = (fidx & 15) << 2;
            const float4v va = *(const float4v*)&A[(size_t)(m0 + row) * K_ + k0 + kc];
            union { ushort_t u[4]; unsigned long long ll; } pa;
            pa.u[0] = f2bf(va.x); pa.u[1] = f2bf(va.y);
            pa.u[2] = f2bf(va.z); pa.u[3] = f2bf(va.w);
            *(unsigned long long*)&As[row * 64 + kc] = pa.ll;
            const int gn = n0 + row;
            float4v vb = (float4v){0.f, 0.f, 0.f, 0.f};
            if (gn < V_) vb = *(const float4v*)&W[(size_t)gn * K_ + k0 + kc];
            union { ushort_t u[4]; unsigned long long ll; } pb;
            pb.u[0] = f2bf(vb.x); pb.u[1] = f2bf(vb.y);
            pb.u[2] = f2bf(vb.z); pb.u[3] = f2bf(vb.w);
            *(unsigned long long*)&Bs[row * 64 + kc] = pb.ll;
        }
        __syncthreads();
        #pragma unroll
        for (int kk = 0; kk < 64; kk += 32) {
            short8 af[4], bf[4];
            #pragma unroll
            for (int t = 0; t < 4; ++t) {
                af[t] = *(const short8*)&As[(wm * 64 + t * 16 + (lane & 15)) * 64 + kk + (lane >> 4) * 8];
                bf[t] = *(const short8*)&Bs[(wn * 64 + t * 16 + (lane & 15)) * 64 + kk + (lane >> 4) * 8];
            }
            #pragma unroll
            for (int mt = 0; mt < 4; ++mt)
                #pragma unroll
                for (int nt = 0; nt < 4; ++nt)
                    acc[mt][nt] = __builtin_amdgcn_mfma_f32_16x16x32_bf16(
                        af[mt], bf[nt], acc[mt][nt], 0, 0, 0);
        }
        __syncthreads();
    }
    #pragma unroll
    for (int mt = 0; mt < 4; ++mt) {
        const int rbase = m0 + wm * 64 + mt * 16 + (lane >> 4) * 4;
        #pragma unroll
        for (int nt = 0; nt < 4; ++nt) {
            const int col = n0 + wn * 64 + nt * 16 + (lane & 15);
            if (col < V_) {
                const float bv = bias[col];
                #pragma unroll
                for (int r = 0; r < 4; ++r)
                    out[(size_t)(rbase + r) * V_ + col] = acc[mt][nt][r] + bv;
            }
        }
    }
}

__global__ __launch_bounds__(256) void rowstats(
    const float* __restrict__ logits, const float* __restrict__ attn,
    const int* __restrict__ src, const int* __restrict__ alignment,
    float* __restrict__ Ai, float* __restrict__ c0v, float* __restrict__ c4v,
    float* __restrict__ tval)
{
    const int i   = blockIdx.x;
    const int b   = i & (B_ - 1);
    const int tid = threadIdx.x;
    const float* row = &logits[(size_t)i * V_];
    float local = 0.f;
    for (int x = tid; x < V_ / 4; x += 256) {
        const float4v v = *(const float4v*)&row[x * 4];
        local += __expf(v.x) + __expf(v.y) + __expf(v.z) + __expf(v.w);
    }
    __shared__ float red[4];
    float s = local;
    #pragma unroll
    for (int off = 32; off > 0; off >>= 1) s += __shfl_down(s, off);
    if ((tid & 63) == 0) red[tid >> 6] = s;
    __shared__ int   sj[S_];
    __shared__ float sat[S_];
    if (tid < S_) {
        sj[tid]  = alignment[src[b * S_ + tid]];
        sat[tid] = attn[i * S_ + tid];
    }
    __syncthreads();
    __shared__ float sh[3];
    if (tid == 0) {
        const float l4   = row[4];
        const float Z    = red[0] + red[1] + red[2] + red[3] - __expf(l4);
        const float copy = 1.f / (1.f + __expf(-l4));
        const float l0   = row[0];
        float anz = 0.f, a4 = 0.f;
        for (int t = 0; t < S_; ++t) {
            anz += (sj[t] != 0) ? sat[t] : 0.f;
            a4  += (sj[t] == 4) ? sat[t] : 0.f;
        }
        const float norm = (1.f - copy) * (1.f - __expf(l0) / Z) + copy * anz + EPS;
        Ai[i]  = (1.f - copy) / (Z * norm);
        c0v[i] = __logf(EPS / norm + EPS);
        c4v[i] = __logf(copy * a4 / norm + EPS);
        sh[0] = Z; sh[1] = copy; sh[2] = norm;
    }
    __syncthreads();
    if (tid < S_) {
        const float Z = sh[0], copy = sh[1], norm = sh[2];
        const int j = sj[tid];
        float val;
        if (j == 0) {
            val = __logf(EPS / norm + EPS);
        } else {
            float sum = 0.f;
            for (int t = 0; t < S_; ++t) sum += (sj[t] == j) ? sat[t] : 0.f;
            const float pj = (j == 4) ? 0.f : __expf(row[j]) * (1.f - copy) / Z;
            val = __logf((pj + copy * sum) / norm + EPS);
        }
        tval[i * S_ + tid] = val;
    }
}
// ===========================================================================

extern "C" void kernel_launch(void* const* d_in, const int* in_sizes, int n_in,
                              void* d_out, int out_size, void* d_ws, size_t ws_size,
                              hipStream_t stream)
{
    const float* hidden    = (const float*)d_in[0];
    const float* attn      = (const float*)d_in[1];
    const float* W         = (const float*)d_in[2];
    const float* bias      = (const float*)d_in[3];
    const int*   src       = (const int*)d_in[4];
    const int*   alignment = (const int*)d_in[5];
    float* out = (float*)d_out;

    float* ws   = (float*)d_ws;
    float* Zp   = ws;            // 2048
    float* Ai   = ws + 2048;     // 2048
    float* c0v  = ws + 4096;     // 2048
    float* c4v  = ws + 6144;     // 2048
    float* tval = ws + 8192;     // 2048*50
    // bf16 buffers after the float area (16B-aligned offsets)
    const size_t hdr_floats = 8192 + (size_t)M_ * S_;          // 110592
    ushort_t* Wbf = (ushort_t*)(ws + hdr_floats);              // VPAD x K
    ushort_t* Hbf = Wbf + (size_t)VPAD_ * K_;                  // M x K
    const size_t need = hdr_floats * 4 + ((size_t)VPAD_ * K_ + (size_t)M_ * K_) * 2;

    if (ws_size >= need) {
        zeroZ<<<(M_ + 255) / 256, 256, 0, stream>>>(Zp);
        convert_w<<<(VPAD_ * (K_ / 8) + 255) / 256, 256, 0, stream>>>(W, Wbf);
        convert_h<<<(M_ * (K_ / 8)) / 256, 256, 0, stream>>>(hidden, Hbf);
        dim3 g1(M_ / 128, VPAD_ / 128);   // 16 x 391
        gemm_fast<<<g1, 256, 0, stream>>>(Hbf, Wbf, bias, out, Zp);
        stats<<<M_, 64, 0, stream>>>(out, attn, src, alignment, Zp, Ai, c0v, c4v, tval);
    } else {
        dim3 g1(M_ / 128, (V_ + 127) / 128);
        gemm_logits<<<g1, 256, 0, stream>>>(hidden, W, bias, out);
        rowstats<<<M_, 256, 0, stream>>>(out, attn, src, alignment, Ai, c0v, c4v, tval);
    }
    transform<<<dim3((V_ / 4 + 255) / 256, M_), 256, 0, stream>>>(out, Ai);
    fixup<<<M_, 64, 0, stream>>>(out, src, alignment, tval, c0v, c4v);
}